// Round 2
// baseline (821.103 us; speedup 1.0000x reference)
//
#include <hip/hip_runtime.h>

// out[b,i] = exp(l-d) / (exp(l-d) + rowsum - exp(l))
//          = e*s / (e*(s-1) + rowsum),  e = exp(l), s = exp(-d)
//
// 4096 rows x 32000 cols fp32. One block per row, 512 threads (8 waves),
// 16 float4 per thread kept in registers (last iteration tail-predicated:
// 8000 float4/row = 15*512 + 320). Single global read of logits, single
// write of out -> 1.07 GB minimum HBM traffic.
//
// e[16] = 64 VGPRs vs previous e[25] = 100: target ~5 waves/SIMD occupancy
// instead of ~3 so the read-phase latency and the reduce barrier are hidden.

#define COLS 32000
#define NF4 (COLS / 4)       // 8000 float4 per row
#define BLOCK 512
#define VFULL 15             // full iterations: 15*512 = 7680
#define TAIL (NF4 - VFULL * BLOCK)  // 320 threads active in last iter
#define VPT 16

__global__ __launch_bounds__(BLOCK) void soft_margin_softmax_kernel(
    const float* __restrict__ logits,
    const float* __restrict__ dist,
    float* __restrict__ out) {
    const int row = blockIdx.x;
    const int tid = threadIdx.x;

    const float4* __restrict__ lrow =
        reinterpret_cast<const float4*>(logits + (size_t)row * COLS);
    float4* __restrict__ orow =
        reinterpret_cast<float4*>(out + (size_t)row * COLS);

    const float s = __expf(-dist[0]);

    float4 e[VPT];
    float local = 0.0f;
#pragma unroll
    for (int i = 0; i < VFULL; ++i) {
        float4 l = lrow[tid + i * BLOCK];
        float4 ev;
        ev.x = __expf(l.x);
        ev.y = __expf(l.y);
        ev.z = __expf(l.z);
        ev.w = __expf(l.w);
        e[i] = ev;
        local += (ev.x + ev.y) + (ev.z + ev.w);
    }
    const bool tail_active = tid < TAIL;
    if (tail_active) {
        float4 l = lrow[tid + VFULL * BLOCK];
        float4 ev;
        ev.x = __expf(l.x);
        ev.y = __expf(l.y);
        ev.z = __expf(l.z);
        ev.w = __expf(l.w);
        e[VFULL] = ev;
        local += (ev.x + ev.y) + (ev.z + ev.w);
    }

    // wave64 butterfly-free down-reduction
#pragma unroll
    for (int off = 32; off > 0; off >>= 1)
        local += __shfl_down(local, off, 64);

    __shared__ float wsum[BLOCK / 64];
    const int wid = tid >> 6;
    const int lane = tid & 63;
    if (lane == 0) wsum[wid] = local;
    __syncthreads();

    const float rowsum = ((wsum[0] + wsum[1]) + (wsum[2] + wsum[3])) +
                         ((wsum[4] + wsum[5]) + (wsum[6] + wsum[7]));
    const float sm1 = s - 1.0f;

#pragma unroll
    for (int i = 0; i < VFULL; ++i) {
        float4 ev = e[i];
        float4 o;
        o.x = __fdividef(ev.x * s, ev.x * sm1 + rowsum);
        o.y = __fdividef(ev.y * s, ev.y * sm1 + rowsum);
        o.z = __fdividef(ev.z * s, ev.z * sm1 + rowsum);
        o.w = __fdividef(ev.w * s, ev.w * sm1 + rowsum);
        orow[tid + i * BLOCK] = o;
    }
    if (tail_active) {
        float4 ev = e[VFULL];
        float4 o;
        o.x = __fdividef(ev.x * s, ev.x * sm1 + rowsum);
        o.y = __fdividef(ev.y * s, ev.y * sm1 + rowsum);
        o.z = __fdividef(ev.z * s, ev.z * sm1 + rowsum);
        o.w = __fdividef(ev.w * s, ev.w * sm1 + rowsum);
        orow[tid + VFULL * BLOCK] = o;
    }
}

extern "C" void kernel_launch(void* const* d_in, const int* in_sizes, int n_in,
                              void* d_out, int out_size, void* d_ws, size_t ws_size,
                              hipStream_t stream) {
    const float* logits = (const float*)d_in[0];
    const float* dist = (const float*)d_in[1];
    float* out = (float*)d_out;
    const int rows = out_size / COLS;  // 4096
    soft_margin_softmax_kernel<<<rows, BLOCK, 0, stream>>>(logits, dist, out);
}

// Round 6
// 802.852 us; speedup vs baseline: 1.0227x; 1.0227x over previous
//
#include <hip/hip_runtime.h>

// out[b,i] = exp(l-d) / (exp(l-d) + rowsum - exp(l))
//          = e*s / (e*(s-1) + rowsum),  e = exp(l), s = exp(-d)
//
// 4096 rows x 32000 cols fp32. One block per row, 512 threads (8 waves),
// 16 float4 per thread kept in registers. Single global read of logits,
// single write of out -> 1.07 GB minimum HBM traffic (roofline ~170 us).
//
// R2 lesson: occupancy 3->5 waves/SIMD moved nothing -> BW-bound, not
// latency-bound. This round: nontemporal loads/stores (streaming data,
// zero reuse). R4 fix: nontemporal builtins need a NATIVE clang vector
// type, not HIP_vector_type -> use ext_vector_type(4) float.

#define COLS 32000
#define NF4 (COLS / 4)       // 8000 float4 per row
#define BLOCK 512
#define VFULL 15             // full iterations: 15*512 = 7680
#define TAIL (NF4 - VFULL * BLOCK)  // 320 threads active in last iter
#define VPT 16

typedef float vf4 __attribute__((ext_vector_type(4)));

__global__ __launch_bounds__(BLOCK) void soft_margin_softmax_kernel(
    const float* __restrict__ logits,
    const float* __restrict__ dist,
    float* __restrict__ out) {
    const int row = blockIdx.x;
    const int tid = threadIdx.x;

    const vf4* __restrict__ lrow =
        reinterpret_cast<const vf4*>(logits + (size_t)row * COLS);
    vf4* __restrict__ orow =
        reinterpret_cast<vf4*>(out + (size_t)row * COLS);

    const float s = __expf(-dist[0]);

    vf4 e[VPT];
    float local = 0.0f;
#pragma unroll
    for (int i = 0; i < VFULL; ++i) {
        vf4 l = __builtin_nontemporal_load(&lrow[tid + i * BLOCK]);
        vf4 ev;
        ev.x = __expf(l.x);
        ev.y = __expf(l.y);
        ev.z = __expf(l.z);
        ev.w = __expf(l.w);
        e[i] = ev;
        local += (ev.x + ev.y) + (ev.z + ev.w);
    }
    const bool tail_active = tid < TAIL;
    if (tail_active) {
        vf4 l = __builtin_nontemporal_load(&lrow[tid + VFULL * BLOCK]);
        vf4 ev;
        ev.x = __expf(l.x);
        ev.y = __expf(l.y);
        ev.z = __expf(l.z);
        ev.w = __expf(l.w);
        e[VFULL] = ev;
        local += (ev.x + ev.y) + (ev.z + ev.w);
    }

    // wave64 down-reduction
#pragma unroll
    for (int off = 32; off > 0; off >>= 1)
        local += __shfl_down(local, off, 64);

    __shared__ float wsum[BLOCK / 64];
    const int wid = tid >> 6;
    const int lane = tid & 63;
    if (lane == 0) wsum[wid] = local;
    __syncthreads();

    const float rowsum = ((wsum[0] + wsum[1]) + (wsum[2] + wsum[3])) +
                         ((wsum[4] + wsum[5]) + (wsum[6] + wsum[7]));
    const float sm1 = s - 1.0f;

#pragma unroll
    for (int i = 0; i < VFULL; ++i) {
        vf4 ev = e[i];
        vf4 o;
        o.x = __fdividef(ev.x * s, ev.x * sm1 + rowsum);
        o.y = __fdividef(ev.y * s, ev.y * sm1 + rowsum);
        o.z = __fdividef(ev.z * s, ev.z * sm1 + rowsum);
        o.w = __fdividef(ev.w * s, ev.w * sm1 + rowsum);
        __builtin_nontemporal_store(o, &orow[tid + i * BLOCK]);
    }
    if (tail_active) {
        vf4 ev = e[VFULL];
        vf4 o;
        o.x = __fdividef(ev.x * s, ev.x * sm1 + rowsum);
        o.y = __fdividef(ev.y * s, ev.y * sm1 + rowsum);
        o.z = __fdividef(ev.z * s, ev.z * sm1 + rowsum);
        o.w = __fdividef(ev.w * s, ev.w * sm1 + rowsum);
        __builtin_nontemporal_store(o, &orow[tid + VFULL * BLOCK]);
    }
}

extern "C" void kernel_launch(void* const* d_in, const int* in_sizes, int n_in,
                              void* d_out, int out_size, void* d_ws, size_t ws_size,
                              hipStream_t stream) {
    const float* logits = (const float*)d_in[0];
    const float* dist = (const float*)d_in[1];
    float* out = (float*)d_out;
    const int rows = out_size / COLS;  // 4096
    soft_margin_softmax_kernel<<<rows, BLOCK, 0, stream>>>(logits, dist, out);
}